// Round 1
// baseline (464.609 us; speedup 1.0000x reference)
//
#include <hip/hip_runtime.h>

#define HIDDEN 2048
#define NHEADS 32
#define NKV    8
#define HDIM   64
#define BATCH  2
#define SEQ    2048
#define MROWS  (BATCH*SEQ)          // 4096
#define NQKV   3072                 // 2048 Q + 512 K + 512 V

typedef _Float16 half8_t __attribute__((ext_vector_type(8)));
typedef _Float16 half4_t __attribute__((ext_vector_type(4)));
typedef float    f32x4_t __attribute__((ext_vector_type(4)));

#define AS1 __attribute__((address_space(1)))
#define AS3 __attribute__((address_space(3)))

__device__ __forceinline__ void async_copy16(void* lds, const void* g) {
    // HW semantics: LDS dest = wave-uniform base + lane*16 (m104/m108)
    __builtin_amdgcn_global_load_lds((AS1 void*)g, (AS3 void*)lds, 16, 0, 0);
}

// ---------------------------------------------------------------------------
// NT GEMM: C[m][n] = sum_k A[m][k] * B[n][k] + bias[n]
// A [M][K] fp16 row-major, B [N][K] fp16 row-major. 128x128 tile, BK=32.
// 256 threads = 4 waves, each wave does a 64x64 quadrant (4x4 of 16x16 MFMA).
// ---------------------------------------------------------------------------
template <typename OutT>
__global__ __launch_bounds__(256) void gemm_nt(
    const _Float16* __restrict__ A, const _Float16* __restrict__ Bm,
    const float* __restrict__ bias, OutT* __restrict__ C,
    int M, int N, int K) {
    __shared__ _Float16 As[128 * 32];
    __shared__ _Float16 Bs[128 * 32];

    const int tid  = threadIdx.x;
    const int wave = tid >> 6;
    const int lane = tid & 63;
    const int quad = lane >> 4;
    const int l16  = lane & 15;
    const int m0 = blockIdx.y * 128;
    const int n0 = blockIdx.x * 128;
    const int mw = (wave & 1) * 64;
    const int nw = (wave >> 1) * 64;

    f32x4_t acc[4][4] = {};

    const int srow = tid >> 2;            // 0..63
    const int scol = (tid & 3) * 8;       // 0,8,16,24
    const _Float16* Ag = A  + (size_t)(m0 + srow) * K + scol;
    const _Float16* Bg = Bm + (size_t)(n0 + srow) * K + scol;
    char* AsB = (char*)As + (size_t)wave * 1024;   // wave-uniform LDS base
    char* BsB = (char*)Bs + (size_t)wave * 1024;

    for (int k0 = 0; k0 < K; k0 += 32) {
        __syncthreads();
        async_copy16(AsB,        Ag + k0);
        async_copy16(AsB + 4096, Ag + (size_t)64 * K + k0);
        async_copy16(BsB,        Bg + k0);
        async_copy16(BsB + 4096, Bg + (size_t)64 * K + k0);
        __syncthreads();

        half8_t a[4], b[4];
#pragma unroll
        for (int i = 0; i < 4; ++i)
            a[i] = *(const half8_t*)(As + (mw + i * 16 + l16) * 32 + quad * 8);
#pragma unroll
        for (int i = 0; i < 4; ++i)
            b[i] = *(const half8_t*)(Bs + (nw + i * 16 + l16) * 32 + quad * 8);
#pragma unroll
        for (int mi = 0; mi < 4; ++mi)
#pragma unroll
            for (int ni = 0; ni < 4; ++ni)
                acc[mi][ni] = __builtin_amdgcn_mfma_f32_16x16x32_f16(
                    a[mi], b[ni], acc[mi][ni], 0, 0, 0);
    }

#pragma unroll
    for (int mi = 0; mi < 4; ++mi) {
#pragma unroll
        for (int ni = 0; ni < 4; ++ni) {
            const int c = n0 + nw + ni * 16 + l16;
            const float bv = bias[c];
#pragma unroll
            for (int i = 0; i < 4; ++i) {
                const int r = m0 + mw + mi * 16 + quad * 4 + i;
                C[(size_t)r * N + c] = (OutT)(acc[mi][ni][i] + bv);
            }
        }
    }
}

// ---------------------------------------------------------------------------
// Flash-style GQA attention. Grid: (S/64, B*NHEADS). Block: 256 (4 waves).
// Each wave owns 16 Q rows. K-tiles of 128 keys, online softmax, PV via
// LDS round-trip of P (per-wave region) and transposed V.
// scale folded into Q at projection time.
// ctx written [b][h][s][d] fp16 (the reference's buggy reshape makes this
// directly the A-matrix of the output GEMM).
// ---------------------------------------------------------------------------
__global__ __launch_bounds__(256) void attn_kernel(
    const _Float16* __restrict__ qkv, _Float16* __restrict__ ctx) {
    __shared__ _Float16 Ks[128 * 72];       // [key][d]  pad 64->72
    __shared__ _Float16 Vt[64 * 136];       // [d][key]  pad 128->136
    __shared__ _Float16 Pw[4][16 * 136];    // per-wave P [row][key]

    const int tid  = threadIdx.x;
    const int wave = tid >> 6;
    const int lane = tid & 63;
    const int quad = lane >> 4;
    const int l16  = lane & 15;
    const int qt = blockIdx.x;              // 0..31
    const int bh = blockIdx.y;              // 0..63
    const int b  = bh >> 5;
    const int h  = bh & 31;
    const int kv = h >> 2;
    const size_t rowbase = (size_t)b * SEQ;

    // Q fragments (A operand: m = lane&15, k = quad*8+j), stay in registers
    const int qrow = qt * 64 + wave * 16 + l16;
    const _Float16* qptr = qkv + (rowbase + qrow) * NQKV + h * 64 + quad * 8;
    const half8_t qa0 = *(const half8_t*)qptr;
    const half8_t qa1 = *(const half8_t*)(qptr + 32);

    f32x4_t o[4] = {};
    float mrow[4] = {-1e30f, -1e30f, -1e30f, -1e30f};
    float lrow[4] = {0.f, 0.f, 0.f, 0.f};

    const int srow = tid >> 1;              // 0..127 (key row for staging)
    const int scol = (tid & 1) * 32;        // 0 or 32
    const _Float16* kg = qkv + rowbase * NQKV + 2048 + kv * 64 + scol;
    const _Float16* vg = qkv + rowbase * NQKV + 2560 + kv * 64 + scol;

    for (int kt = 0; kt < SEQ / 128; ++kt) {
        __syncthreads();
        {   // stage K tile [128][64] -> Ks (row-major, padded 72)
            const _Float16* kp = kg + (size_t)(kt * 128 + srow) * NQKV;
            half8_t k0 = *(const half8_t*)(kp);
            half8_t k1 = *(const half8_t*)(kp + 8);
            half8_t k2 = *(const half8_t*)(kp + 16);
            half8_t k3 = *(const half8_t*)(kp + 24);
            *(half8_t*)(Ks + srow * 72 + scol)      = k0;
            *(half8_t*)(Ks + srow * 72 + scol + 8)  = k1;
            *(half8_t*)(Ks + srow * 72 + scol + 16) = k2;
            *(half8_t*)(Ks + srow * 72 + scol + 24) = k3;
            // stage V tile transposed -> Vt[d][key]
            const _Float16* vp = vg + (size_t)(kt * 128 + srow) * NQKV;
            half8_t v0 = *(const half8_t*)(vp);
            half8_t v1 = *(const half8_t*)(vp + 8);
            half8_t v2 = *(const half8_t*)(vp + 16);
            half8_t v3 = *(const half8_t*)(vp + 24);
#pragma unroll
            for (int j = 0; j < 8; ++j) {
                Vt[(scol + j) * 136 + srow]      = v0[j];
                Vt[(scol + 8 + j) * 136 + srow]  = v1[j];
                Vt[(scol + 16 + j) * 136 + srow] = v2[j];
                Vt[(scol + 24 + j) * 136 + srow] = v3[j];
            }
        }
        __syncthreads();

        // QK^T: 16 rows x 128 keys per wave
        f32x4_t sc[8];
#pragma unroll
        for (int nt = 0; nt < 8; ++nt) {
            const half8_t kb0 = *(const half8_t*)(Ks + (nt * 16 + l16) * 72 + quad * 8);
            const half8_t kb1 = *(const half8_t*)(Ks + (nt * 16 + l16) * 72 + 32 + quad * 8);
            f32x4_t s = {};
            s = __builtin_amdgcn_mfma_f32_16x16x32_f16(qa0, kb0, s, 0, 0, 0);
            s = __builtin_amdgcn_mfma_f32_16x16x32_f16(qa1, kb1, s, 0, 0, 0);
            sc[nt] = s;
        }

        // online softmax (rows r = quad*4+i; reduce across lane&15)
        float rmax[4], alpha[4], rsum[4];
#pragma unroll
        for (int i = 0; i < 4; ++i) {
            float mx = sc[0][i];
#pragma unroll
            for (int nt = 1; nt < 8; ++nt) mx = fmaxf(mx, sc[nt][i]);
#pragma unroll
            for (int msk = 1; msk < 16; msk <<= 1)
                mx = fmaxf(mx, __shfl_xor(mx, msk, 64));
            const float mnew = fmaxf(mrow[i], mx);
            alpha[i] = __expf(mrow[i] - mnew);
            mrow[i] = mnew;
            rsum[i] = 0.f;
        }
        _Float16* myP = Pw[wave];
#pragma unroll
        for (int nt = 0; nt < 8; ++nt) {
#pragma unroll
            for (int i = 0; i < 4; ++i) {
                const float p = __expf(sc[nt][i] - mrow[i]);
                rsum[i] += p;
                myP[(quad * 4 + i) * 136 + nt * 16 + l16] = (_Float16)p;
            }
        }
#pragma unroll
        for (int i = 0; i < 4; ++i) {
#pragma unroll
            for (int msk = 1; msk < 16; msk <<= 1)
                rsum[i] += __shfl_xor(rsum[i], msk, 64);
            lrow[i] = lrow[i] * alpha[i] + rsum[i];
        }
#pragma unroll
        for (int dt = 0; dt < 4; ++dt)
#pragma unroll
            for (int i = 0; i < 4; ++i) o[dt][i] *= alpha[i];

        __syncthreads();   // P visible (cross-lane), Vt stable

        // PV: o[16 rows][64 d] += P[16][128] * V[128][64]
#pragma unroll
        for (int kc = 0; kc < 4; ++kc) {
            const half8_t pa = *(const half8_t*)(myP + l16 * 136 + kc * 32 + quad * 8);
#pragma unroll
            for (int dt = 0; dt < 4; ++dt) {
                const half8_t vb = *(const half8_t*)(Vt + (dt * 16 + l16) * 136 + kc * 32 + quad * 8);
                o[dt] = __builtin_amdgcn_mfma_f32_16x16x32_f16(pa, vb, o[dt], 0, 0, 0);
            }
        }
    }

    // epilogue: divide by l, write ctx[b][h][s][d]
#pragma unroll
    for (int i = 0; i < 4; ++i) {
        const float inv = 1.f / lrow[i];
        const size_t s = (size_t)qt * 64 + wave * 16 + quad * 4 + i;
#pragma unroll
        for (int dt = 0; dt < 4; ++dt) {
            ctx[((size_t)bh * SEQ + s) * 64 + dt * 16 + l16] =
                (_Float16)(o[dt][i] * inv);
        }
    }
}

// ---------------------------------------------------------------------------
// casts / packing
// ---------------------------------------------------------------------------
__global__ void cast_f2h(const float* __restrict__ s, _Float16* __restrict__ d,
                         int n4, float scale) {
    const int i = blockIdx.x * blockDim.x + threadIdx.x;
    if (i < n4) {
        const f32x4_t v = ((const f32x4_t*)s)[i];
        half4_t h;
#pragma unroll
        for (int j = 0; j < 4; ++j) h[j] = (_Float16)(v[j] * scale);
        ((half4_t*)d)[i] = h;
    }
}

__global__ void pack_bias(const float* __restrict__ bq, const float* __restrict__ bk,
                          const float* __restrict__ bv, float* __restrict__ out) {
    const int i = blockIdx.x * blockDim.x + threadIdx.x;
    if (i < 2048)      out[i] = bq[i] * 0.125f;
    else if (i < 2560) out[i] = bk[i - 2048];
    else if (i < 3072) out[i] = bv[i - 2560];
}

// ---------------------------------------------------------------------------
extern "C" void kernel_launch(void* const* d_in, const int* in_sizes, int n_in,
                              void* d_out, int out_size, void* d_ws, size_t ws_size,
                              hipStream_t stream) {
    const float* X  = (const float*)d_in[0];
    const float* Wq = (const float*)d_in[1];
    const float* bq = (const float*)d_in[2];
    const float* Wk = (const float*)d_in[3];
    const float* bk = (const float*)d_in[4];
    const float* Wv = (const float*)d_in[5];
    const float* bv = (const float*)d_in[6];
    const float* Wo = (const float*)d_in[7];
    const float* bo = (const float*)d_in[8];
    float* out = (float*)d_out;

    char* p = (char*)d_ws;
    _Float16* Xh   = (_Float16*)p; p += (size_t)MROWS * HIDDEN * 2;   // 16.8 MB (reused as ctx)
    _Float16* Wqkv = (_Float16*)p; p += (size_t)NQKV * HIDDEN * 2;    // 12.6 MB
    _Float16* Woh  = (_Float16*)p; p += (size_t)HIDDEN * HIDDEN * 2;  //  8.4 MB
    float*    bqkv = (float*)p;    p += (size_t)NQKV * 4;
    _Float16* QKV  = (_Float16*)p; p += (size_t)MROWS * NQKV * 2;     // 25.2 MB
    _Float16* ctx  = Xh;  // alias: Xh dead after QKV GEMM

    // casts (scale 1/sqrt(64)=0.125 folded into Wq/bq)
    cast_f2h<<<8192, 256, 0, stream>>>(X, Xh, MROWS * HIDDEN / 4, 1.f);
    cast_f2h<<<4096, 256, 0, stream>>>(Wq, Wqkv, HIDDEN * HIDDEN / 4, 0.125f);
    cast_f2h<<<1024, 256, 0, stream>>>(Wk, Wqkv + (size_t)HIDDEN * HIDDEN, 512 * HIDDEN / 4, 1.f);
    cast_f2h<<<1024, 256, 0, stream>>>(Wv, Wqkv + (size_t)(HIDDEN + 512) * HIDDEN, 512 * HIDDEN / 4, 1.f);
    cast_f2h<<<4096, 256, 0, stream>>>(Wo, Woh, HIDDEN * HIDDEN / 4, 1.f);
    pack_bias<<<12, 256, 0, stream>>>(bq, bk, bv, bqkv);

    // QKV projection: [4096 x 2048] x [3072 x 2048]^T -> fp16 [4096 x 3072]
    gemm_nt<_Float16><<<dim3(NQKV / 128, MROWS / 128), 256, 0, stream>>>(
        Xh, Wqkv, bqkv, QKV, MROWS, NQKV, HIDDEN);

    // attention -> ctx [b][h][s][d] fp16
    attn_kernel<<<dim3(SEQ / 64, BATCH * NHEADS), 256, 0, stream>>>(QKV, ctx);

    // output projection: ctx (viewed [4096 x 2048]) x Wo^T + bo -> fp32 d_out
    gemm_nt<float><<<dim3(HIDDEN / 128, MROWS / 128), 256, 0, stream>>>(
        ctx, Woh, bo, out, MROWS, HIDDEN, HIDDEN);
}